// Round 2
// baseline (481.656 us; speedup 1.0000x reference)
//
#include <hip/hip_runtime.h>

// HyperConnections fused kernel (fp32 I/O, fp32 math) — v3: token-per-wave.
//
// out[t,:] = residual[t,:] * (SB + E*tanh(dotB*inv_rms)*beta_scale)
//          + x[t,:]        * (SA + E*sum_{i=1..E} tanh(dotA_i*inv_rms)*alpha_scale)
// dotA_i = sum_d x[d]*w[d]*fnA[d][i] (i=1..E; fnA column 0 provably unused),
// dotB   = sum_d x[d]*w[d]*fnB[d],  inv_rms = rsqrt(mean(x^2)+eps).
//
// v3 vs v2 (which was latency-bound: 4-wave barrier lock-step per token,
// HBM 27%, VALU 14%):
//  - combined weights staged ONCE per block into LDS, column-major float4:
//    wcol[i][g] (i=0..3: w*fnA[:,i+1]; i=4: w*fnB), g = d/4. Main-loop reads
//    are contiguous 1KB ds_read_b128 per array — conflict-free.
//  - each WAVE owns TPW=4 consecutive tokens; the reduction is wave-local
//    (butterfly) -> ZERO barriers / LDS round-trips in the main loop. Waves
//    drift independently, each keeping ~16KB of loads in flight (x[t+1]
//    prefetch + resid[t]) -> outstanding bytes per CU >> BW-saturation need.
//  - grid = n_tokens/(4 waves * TPW) = 1024 blocks = 4 blocks/CU (40KB LDS
//    cap), everything resident in one round.

#define D_MODEL 2048
#define E_RATE 4
#define HC_EPS 1e-5f
#define NT 256
#define TPW 4                     // tokens per wave
#define F4ROW (D_MODEL / 4)       // 512 float4 per token row
#define CHUNKS 8                  // 8 float4 per lane = 32 elems = 2048/64

__device__ __forceinline__ float fast_tanh(float z) {
    // tanh(z) = 1 - 2/(exp2(z*2*log2(e)) + 1); exact 0 at z=0, saturates +-1.
    const float e = __builtin_amdgcn_exp2f(z * 2.8853900817779268f);
    return fmaf(-2.0f, __builtin_amdgcn_rcpf(e + 1.0f), 1.0f);
}

extern "C" __global__ void __launch_bounds__(NT, 3)
hc_kernel(const float* __restrict__ x,
          const float* __restrict__ resid,
          const float* __restrict__ w,
          const float* __restrict__ sA,     // [E, E+1] = [4,5]
          const float* __restrict__ sB,     // [E]
          const float* __restrict__ fnA,    // [D, E+1]
          const float* __restrict__ aScale, // [1]
          const float* __restrict__ fnB,    // [D]
          const float* __restrict__ bScale, // [1]
          float* __restrict__ out,
          const int n_tokens)
{
    const int tid  = threadIdx.x;
    const int wave = tid >> 6, lane = tid & 63;

    // wcol[i][g]: i=0..3 -> w*fnA[:,i+1], i=4 -> w*fnB; g = d/4. 40 KB.
    __shared__ float4 wcol[5][512];

    // ---- stage combined weights (once per block). Thread tid owns d = tid*8..tid*8+7.
    {
        float4 w0 = ((const float4*)w)[2 * tid];
        float4 w1 = ((const float4*)w)[2 * tid + 1];
        float4 b0 = ((const float4*)fnB)[2 * tid];
        float4 b1 = ((const float4*)fnB)[2 * tid + 1];
        float wf[8]  = {w0.x, w0.y, w0.z, w0.w, w1.x, w1.y, w1.z, w1.w};
        float fbf[8] = {b0.x, b0.y, b0.z, b0.w, b1.x, b1.y, b1.z, b1.w};

        float fa[40];  // fnA rows d..d+7 = 40 consecutive floats at tid*40
        const float4* fa4 = (const float4*)fnA;
#pragma unroll
        for (int j = 0; j < 10; j++) {
            float4 t4 = fa4[(size_t)tid * 10 + j];
            fa[4 * j + 0] = t4.x; fa[4 * j + 1] = t4.y;
            fa[4 * j + 2] = t4.z; fa[4 * j + 3] = t4.w;
        }
#pragma unroll
        for (int lg = 0; lg < 2; lg++) {
            const int g = tid * 2 + lg;  // per-thread stride 32B -> 2-way (free)
#pragma unroll
            for (int i = 0; i < 4; i++) {
                float4 v;
                v.x = fa[(4 * lg + 0) * 5 + i + 1] * wf[4 * lg + 0];
                v.y = fa[(4 * lg + 1) * 5 + i + 1] * wf[4 * lg + 1];
                v.z = fa[(4 * lg + 2) * 5 + i + 1] * wf[4 * lg + 2];
                v.w = fa[(4 * lg + 3) * 5 + i + 1] * wf[4 * lg + 3];
                wcol[i][g] = v;
            }
            float4 vb;
            vb.x = fbf[4 * lg + 0] * wf[4 * lg + 0];
            vb.y = fbf[4 * lg + 1] * wf[4 * lg + 1];
            vb.z = fbf[4 * lg + 2] * wf[4 * lg + 2];
            vb.w = fbf[4 * lg + 3] * wf[4 * lg + 3];
            wcol[4][g] = vb;
        }
    }

    // ---- uniform scalars ----
    const float SB = sB[0] + sB[1] + sB[2] + sB[3];
    float SA = 0.0f;
#pragma unroll
    for (int i = 1; i <= E_RATE; i++)
#pragma unroll
        for (int j = 0; j < E_RATE; j++) SA += sA[j * (E_RATE + 1) + i];
    const float asc = aScale[0];
    const float bsc = bScale[0];

    __syncthreads();  // the ONLY barrier

    const int gw   = blockIdx.x * (NT / 64) + wave;  // global wave id
    const int tok0 = gw * TPW;
    const int ntok = min(TPW, n_tokens - tok0);
    if (ntok <= 0) return;

    const float4* x4 = (const float4*)x;
    const float4* r4 = (const float4*)resid;
    float4*       o4 = (float4*)out;

    float4 xa[CHUNKS], xb[CHUNKS], ra[CHUNKS];

    // preload x for first token
    {
        const size_t b0 = (size_t)tok0 * F4ROW + lane;
#pragma unroll
        for (int c = 0; c < CHUNKS; c++) xa[c] = x4[b0 + c * 64];
    }

    for (int t = 0; t < ntok; ++t) {
        const size_t rb = (size_t)(tok0 + t) * F4ROW + lane;

        // issue resid loads for this token (consumed at the epilogue ~700cy later)
#pragma unroll
        for (int c = 0; c < CHUNKS; c++) ra[c] = r4[rb + c * 64];
        // issue x loads for the next token (consumed next iteration)
        if (t + 1 < ntok) {
#pragma unroll
            for (int c = 0; c < CHUNKS; c++) xb[c] = x4[rb + F4ROW + c * 64];
        }

        // ---- 6 partials over this lane's 32 elements ----
        float a0 = 0.f, a1 = 0.f, a2 = 0.f, a3 = 0.f, ab = 0.f, ss = 0.f;
#pragma unroll
        for (int c = 0; c < CHUNKS; c++) {
            const int g = c * 64 + lane;  // contiguous 1KB per array: conflict-free
            const float4 xv  = xa[c];
            const float4 wv0 = wcol[0][g];
            const float4 wv1 = wcol[1][g];
            const float4 wv2 = wcol[2][g];
            const float4 wv3 = wcol[3][g];
            const float4 wvb = wcol[4][g];
            ss = fmaf(xv.x, xv.x,  fmaf(xv.y, xv.y,  fmaf(xv.z, xv.z,  fmaf(xv.w, xv.w,  ss))));
            a0 = fmaf(xv.x, wv0.x, fmaf(xv.y, wv0.y, fmaf(xv.z, wv0.z, fmaf(xv.w, wv0.w, a0))));
            a1 = fmaf(xv.x, wv1.x, fmaf(xv.y, wv1.y, fmaf(xv.z, wv1.z, fmaf(xv.w, wv1.w, a1))));
            a2 = fmaf(xv.x, wv2.x, fmaf(xv.y, wv2.y, fmaf(xv.z, wv2.z, fmaf(xv.w, wv2.w, a2))));
            a3 = fmaf(xv.x, wv3.x, fmaf(xv.y, wv3.y, fmaf(xv.z, wv3.z, fmaf(xv.w, wv3.w, a3))));
            ab = fmaf(xv.x, wvb.x, fmaf(xv.y, wvb.y, fmaf(xv.z, wvb.z, fmaf(xv.w, wvb.w, ab))));
        }

        // ---- wave-local butterfly (all lanes end with full sums) ----
        float vals[6] = {a0, a1, a2, a3, ab, ss};
#pragma unroll
        for (int j = 0; j < 6; j++) {
            float v = vals[j];
#pragma unroll
            for (int off = 32; off > 0; off >>= 1) v += __shfl_xor(v, off, 64);
            vals[j] = v;
        }

        const float inv  = rsqrtf(vals[5] * (1.0f / D_MODEL) + HC_EPS);
        const float dynb = fast_tanh(vals[4] * inv) * bsc;
        const float dyna = fast_tanh(vals[0] * inv) + fast_tanh(vals[1] * inv) +
                           fast_tanh(vals[2] * inv) + fast_tanh(vals[3] * inv);
        const float cR = SB + (float)E_RATE * dynb;
        const float cX = SA + (float)E_RATE * (dyna * asc);

        // ---- epilogue: out = resid*cR + x*cX ----
#pragma unroll
        for (int c = 0; c < CHUNKS; c++) {
            float4 o;
            o.x = fmaf(ra[c].x, cR, xa[c].x * cX);
            o.y = fmaf(ra[c].y, cR, xa[c].y * cX);
            o.z = fmaf(ra[c].z, cR, xa[c].z * cX);
            o.w = fmaf(ra[c].w, cR, xa[c].w * cX);
            o4[rb + c * 64] = o;
        }

        // rotate prefetch buffer (renamed away after unroll/copy-prop)
#pragma unroll
        for (int c = 0; c < CHUNKS; c++) xa[c] = xb[c];
    }
}

extern "C" void kernel_launch(void* const* d_in, const int* in_sizes, int n_in,
                              void* d_out, int out_size, void* d_ws, size_t ws_size,
                              hipStream_t stream) {
    const float* x      = (const float*)d_in[0];
    const float* resid  = (const float*)d_in[1];
    const float* w      = (const float*)d_in[2];
    const float* sA     = (const float*)d_in[3];
    const float* sB     = (const float*)d_in[4];
    const float* fnA    = (const float*)d_in[5];
    const float* aScale = (const float*)d_in[6];
    const float* fnB    = (const float*)d_in[7];
    const float* bScale = (const float*)d_in[8];
    float* out          = (float*)d_out;

    const int n_tokens = in_sizes[0] / D_MODEL;       // B*T = 16384
    const int tok_per_block = (NT / 64) * TPW;        // 16
    const int grid = (n_tokens + tok_per_block - 1) / tok_per_block;  // 1024

    hc_kernel<<<grid, NT, 0, stream>>>(x, resid, w, sA, sB, fnA, aScale,
                                       fnB, bScale, out, n_tokens);
}